// Round 13
// baseline (153.362 us; speedup 1.0000x reference)
//
#include <hip/hip_runtime.h>
#include <math.h>

// Problem constants: B=64, N=512, d=64
#define NB 64
#define NN 512
#define ND 64

#define LOG2E 1.4426950408889634f
#define LN2   0.6931471805599453f
#define RING  12                      // prefetch ring depth (columns in flight)
#define NINF  __int_as_float(0xFF800000u)   // -inf

typedef __attribute__((ext_vector_type(8))) short  bf16x8;  // 8 bf16 in 4 VGPRs
typedef __attribute__((ext_vector_type(4))) float  f32x4;

// fp32 -> bf16 bits, round-to-nearest-even (inputs are finite)
static __device__ __forceinline__ unsigned short f2bf(float f) {
    unsigned u = __float_as_uint(f);
    u += 0x7FFFu + ((u >> 16) & 1u);
    return (unsigned short)(u >> 16);
}

// ---------------------------------------------------------------------------
// Kernel 0 (pack): X,Y (f32 row-major) -> bf16 in MFMA-fragment order, plus
// fp32 row norms (R12-proven, unchanged).
// ---------------------------------------------------------------------------
__global__ __launch_bounds__(256) void pack_kernel(const float* __restrict__ X,
                                                   const float* __restrict__ Y,
                                                   unsigned short* __restrict__ Xp,
                                                   unsigned short* __restrict__ Yp,
                                                   float* __restrict__ nx,
                                                   float* __restrict__ ny) {
    const int gid = blockIdx.x * 256 + threadIdx.x;   // row id, 0..NB*NN-1
    const float* src;
    unsigned short* dst;
    float* ndst;
    if (blockIdx.y == 0) { src = X + (size_t)gid * ND; dst = Xp; ndst = nx; }
    else                 { src = Y + (size_t)gid * ND; dst = Yp; ndst = ny; }

    float v[ND];
    float s = 0.f;
    #pragma unroll
    for (int k = 0; k < ND; k += 4) {
        float4 f = *(const float4*)(src + k);
        v[k] = f.x; v[k + 1] = f.y; v[k + 2] = f.z; v[k + 3] = f.w;
        s += f.x * f.x + f.y * f.y + f.z * f.z + f.w * f.w;
    }
    ndst[gid] = s;

    const int b  = gid >> 9;
    const int i  = gid & 511;
    const int it = i >> 4;             // 16-row tile
    const int lm = i & 15;             // row within tile
    #pragma unroll
    for (int h = 0; h < 2; ++h) {
        #pragma unroll
        for (int q = 0; q < 4; ++q) {
            unsigned w[4];
            #pragma unroll
            for (int m = 0; m < 4; ++m) {
                const int c = h * 32 + q * 8 + 2 * m;
                w[m] = (unsigned)f2bf(v[c]) | ((unsigned)f2bf(v[c + 1]) << 16);
            }
            uint4 pkt; pkt.x = w[0]; pkt.y = w[1]; pkt.z = w[2]; pkt.w = w[3];
            *(uint4*)(dst + ((((size_t)b * 32 + it) * 2 + h) << 9)
                          + (size_t)(q * 16 + lm) * 8) = pkt;
        }
    }
}

// ---------------------------------------------------------------------------
// Kernel 1 (MFMA): Wt[b][i][j] = bf16( exp2(16 - log2e*||X[b][i]-Y[b][j]||) )
// TRANSPOSED store vs R12 (soft-DTW is (i<->j, X<->Y)-symmetric since softmin
// is symmetric in up/left — dtw kernel is unchanged, roles relabel).
// Why: the C/D fragment's thread-contiguous dim is j (quad*4+r), so 4 cells
// pack into ONE dwordx2 bf16 store: 64 global_store_short/thread (R12) -> 16
// dwordx2. VMEM instr/thread: 100 -> 40 (cdist was VMEM-issue-bound).
// ---------------------------------------------------------------------------
__global__ __launch_bounds__(256) void cdist_kernel(const unsigned short* __restrict__ Xp,
                                                    const unsigned short* __restrict__ Yp,
                                                    const float* __restrict__ nx,
                                                    const float* __restrict__ ny,
                                                    unsigned short* __restrict__ Wt) {
    const int b  = blockIdx.z;
    const int ib = blockIdx.x * 128;   // i base (X rows)
    const int jb = blockIdx.y * 128;   // j base (Y rows)
    const int t  = threadIdx.x;

    const int wave = t >> 6;
    const int wi   = (wave & 1) * 64;   // i offset of this wave's 64x64 tile
    const int wj   = (wave >> 1) * 64;  // j offset
    const int lane = t & 63;
    const int lm   = lane & 15;
    const int quad = lane >> 4;

    f32x4 acc[4][4];
    #pragma unroll
    for (int mt = 0; mt < 4; ++mt)
        #pragma unroll
        for (int nt = 0; nt < 4; ++nt)
            acc[mt][nt] = (f32x4){0.f, 0.f, 0.f, 0.f};

    const int jt0 = (jb + wj) >> 4;    // Y tile base
    const int it0 = (ib + wi) >> 4;    // X tile base

    #pragma unroll
    for (int h = 0; h < 2; ++h) {
        bf16x8 Af[4], Bf[4];
        #pragma unroll
        for (int mt = 0; mt < 4; ++mt)   // A from Y tiles (m = j dim)
            Af[mt] = *(const bf16x8*)(Yp
                + ((((size_t)b * 32 + jt0 + mt) * 2 + h) << 9) + (size_t)lane * 8);
        #pragma unroll
        for (int nt = 0; nt < 4; ++nt)   // B from X tiles (n = i dim)
            Bf[nt] = *(const bf16x8*)(Xp
                + ((((size_t)b * 32 + it0 + nt) * 2 + h) << 9) + (size_t)lane * 8);
        #pragma unroll
        for (int mt = 0; mt < 4; ++mt)
            #pragma unroll
            for (int nt = 0; nt < 4; ++nt)
                acc[mt][nt] = __builtin_amdgcn_mfma_f32_16x16x32_bf16(
                    Af[mt], Bf[nt], acc[mt][nt], 0, 0, 0);
    }

    // --- epilogue: d2 = ny[j]+nx[i]-2*s; W = exp2(16 - LOG2E*sqrt(max(d2,0)))
    // stored TRANSPOSED: Wt[b][i][j], 4 j-contiguous bf16 per dwordx2.
    float nxv[4];
    float4 nyv[4];
    #pragma unroll
    for (int nt = 0; nt < 4; ++nt)
        nxv[nt] = nx[(size_t)b * NN + ib + wi + nt * 16 + lm];
    #pragma unroll
    for (int mt = 0; mt < 4; ++mt)      // ny[j], j = ..mt*16 + quad*4 + r
        nyv[mt] = *(const float4*)(ny + (size_t)b * NN + jb + wj + mt * 16 + quad * 4);

    #pragma unroll
    for (int nt = 0; nt < 4; ++nt) {
        const int i = ib + wi + nt * 16 + lm;
        unsigned short* Drow = Wt + ((size_t)b * NN + i) * NN + jb + wj;
        #pragma unroll
        for (int mt = 0; mt < 4; ++mt) {
            const float* nyp = (const float*)&nyv[mt];
            unsigned a[4];
            #pragma unroll
            for (int r = 0; r < 4; ++r) {
                float d2 = nyp[r] + nxv[nt] - 2.0f * acc[mt][nt][r];
                float w  = __builtin_amdgcn_exp2f(16.0f - LOG2E * sqrtf(fmaxf(d2, 0.f)));
                a[r] = __float_as_uint(w) + 0x8000u;   // round-half-up to bf16
            }
            uint2 pkt;
            pkt.x = (a[0] >> 16) | (a[1] & 0xFFFF0000u);
            pkt.y = (a[2] >> 16) | (a[3] & 0xFFFF0000u);
            *(uint2*)(Drow + mt * 16 + quad * 4) = pkt;
        }
    }
}

// ---------------------------------------------------------------------------
// Kernel 2: soft-DTW DP — BYTE-IDENTICAL to R11/R12's proven kernel.
// (With the transposed W, lanes now own Y-rows and step over the X index;
// the DP is symmetric so the math is unchanged.)
// ---------------------------------------------------------------------------
static __device__ __forceinline__ void dtw_step(
    bool DOACT, bool DOGUARD, bool DOREN, bool DOCLAMP,
    int ss, int u, int t, const unsigned short* __restrict__ Wb, int ib,
    uint4* ring, float* L, float& diagHold, float& h, float& Otf)
{
    // lane t receives lane t-1's h (prev step); lane 0 gets -inf
    const float recvH = __int_as_float(__builtin_amdgcn_update_dpp(
        (int)0xFF800000, __float_as_int(h), 0x138 /*wave_shr:1*/, 0xf, 0xf, false));

    // activation: adopt neighbor's scale => up0 = 2^0 = 1, exact (R9-proven)
    if (DOACT) { if (ss == t && t > 0) Otf = -recvH; }

    const float up0   = __builtin_amdgcn_exp2f(fminf(recvH + Otf, 80.0f));
    const float diag0 = diagHold;              // 2^16 * F[ib][j-1], stored dom.
    diagHold = up0 * 65536.0f;                 // 2^16 * F[ib][j] for next step

    const int j = ss - t + 1;
    const uint4 c = ring[u];

    // refill slot u for step ss+RING (unconditional; overrun reads are dead)
    {
        int jn = j + RING;
        if (DOCLAMP) jn = jn < 1 ? 1 : jn;     // lower clamp (phase A only)
        ring[u] = *(const uint4*)(Wb + (size_t)(jn - 1) * NN + ib);
    }

    bool act = true;
    if (DOGUARD) act = (j >= 1) && (j <= NN);
    if (act) {
        float dd[8];                           // bf16 -> f32: shl/and, exact
        dd[0] = __uint_as_float(c.x << 16);
        dd[1] = __uint_as_float(c.x & 0xFFFF0000u);
        dd[2] = __uint_as_float(c.y << 16);
        dd[3] = __uint_as_float(c.y & 0xFFFF0000u);
        dd[4] = __uint_as_float(c.z << 16);
        dd[5] = __uint_as_float(c.z & 0xFFFF0000u);
        dd[6] = __uint_as_float(c.w << 16);
        dd[7] = __uint_as_float(c.w & 0xFFFF0000u);

        float pre[8], cc[8];
        pre[0] = diag0 + L[0];                 // diag0 already carries 2^16
        #pragma unroll
        for (int k = 1; k < 8; ++k)            // 2^16*diag + left (off-chain)
            pre[k] = fmaf(65536.0f, L[k - 1], L[k]);
        #pragma unroll
        for (int k = 0; k < 8; ++k) cc[k] = dd[k] * pre[k];
        float r = up0;
        #pragma unroll
        for (int k = 0; k < 8; ++k) {          // the only serial chain: 8 fma
            r = fmaf(dd[k], r, cc[k]);
            L[k] = r;
        }

        if (DOREN) {   // branchless FULL normalization: max(L) -> [1,2)
            float m8 = fmaxf(fmaxf(fmaxf(L[0], L[1]), fmaxf(L[2], L[3])),
                             fmaxf(fmaxf(L[4], L[5]), fmaxf(L[6], L[7])));
            const int   e  = (int)(__float_as_uint(m8) >> 23) - 127;
            const float sc = __uint_as_float((unsigned)(127 - e) << 23); // 2^-e
            #pragma unroll
            for (int k = 0; k < 8; ++k) L[k] *= sc;
            diagHold *= sc;
            Otf -= (float)e;                   // stored = F * 2^Ot invariant
        }

        // absolute log-domain handoff (invariant under renorm)
        h = __builtin_amdgcn_logf(L[7]) - Otf; // v_log_f32 = log2
    }
}

__global__ __launch_bounds__(64) void dtw_kernel(const unsigned short* __restrict__ Wt,
                                                 float* __restrict__ out) {
    const int b = blockIdx.x;
    const int t = threadIdx.x;                 // lane 0..63
    const unsigned short* __restrict__ Wb = Wt + (size_t)b * NN * NN;
    const int ib = 8 * t;                      // first owned row of W column

    float L[8];
    #pragma unroll
    for (int k = 0; k < 8; ++k) L[k] = 0.0f;   // F(inf) = 0 boundary

    float diagHold = (t == 0) ? 65536.0f : 0.0f;  // 2^16 * F[0][0] for lane 0
    float h        = NINF;                     // my bottom row, log2(F) domain
    float Otf      = 0.0f;                     // stored = F * 2^Ot

    // prefetch ring: slot u holds the 8 bf16 W values (one dwordx4) of the
    // column consumed at step ss == u (mod RING).
    uint4 ring[RING];
    #pragma unroll
    for (int u = 0; u < RING; ++u) {
        int col = u - t + 1;
        col = col < 1 ? 1 : col;               // clamp; dead if OOB
        ring[u] = *(const uint4*)(Wb + (size_t)(col - 1) * NN + ib);
    }

    // Phase A: guards + activation + lower clamp (ss 0..71)
    for (int sb = 0; sb < 72; sb += RING)
        #pragma unroll
        for (int u = 0; u < RING; ++u)
            dtw_step(true, true, (u & 1) == 1, true,
                     sb + u, u, t, Wb, ib, ring, L, diagHold, h, Otf);

    // Phase B: branchless hot loop (ss 72..503; all 64 lanes active)
    for (int sb = 72; sb < 504; sb += RING)
        #pragma unroll
        for (int u = 0; u < RING; ++u)
            dtw_step(false, false, (u & 1) == 1, false,
                     sb + u, u, t, Wb, ib, ring, L, diagHold, h, Otf);

    // Phase C: drain with j<=NN guard (ss 504..575)
    for (int sb = 504; sb < 576; sb += RING)
        #pragma unroll
        for (int u = 0; u < RING; ++u)
            dtw_step(false, true, (u & 1) == 1, false,
                     sb + u, u, t, Wb, ib, ring, L, diagHold, h, Otf);

    // R[N][N] = (16*1024 - log2 F) * ln2,  log2 F = h (lane 63, ss=574)
    if (t == 63) out[b] = (16384.0f - h) * LN2;
}

extern "C" void kernel_launch(void* const* d_in, const int* in_sizes, int n_in,
                              void* d_out, int out_size, void* d_ws, size_t ws_size,
                              hipStream_t stream) {
    const float* X = (const float*)d_in[0];
    const float* Y = (const float*)d_in[1];
    float* out = (float*)d_out;

    // workspace layout (ws >= 64 MB):
    //   [0, 32 MB)      Wt  : bf16 W matrix, layout [b][i][j] (transposed)
    //   [32, 36 MB)     Xp  : packed bf16 X fragments
    //   [36, 40 MB)     Yp  : packed bf16 Y fragments
    //   [40 MB, +128KB) nx  : fp32 row norms of X
    //   [+128KB,+256KB) ny  : fp32 row norms of Y
    char* ws = (char*)d_ws;
    unsigned short* Wt = (unsigned short*)(ws);
    unsigned short* Xp = (unsigned short*)(ws + (33554432));
    unsigned short* Yp = (unsigned short*)(ws + (33554432 + 4194304));
    float* nx = (float*)(ws + (33554432 + 2 * 4194304));
    float* ny = (float*)(ws + (33554432 + 2 * 4194304 + 131072));

    pack_kernel<<<dim3(NB * NN / 256, 2), 256, 0, stream>>>(X, Y, Xp, Yp, nx, ny);
    cdist_kernel<<<dim3(4, 4, NB), 256, 0, stream>>>(Xp, Yp, nx, ny, Wt);
    dtw_kernel<<<NB, 64, 0, stream>>>(Wt, out);
}

// Round 14
// 147.292 us; speedup vs baseline: 1.0412x; 1.0412x over previous
//
#include <hip/hip_runtime.h>
#include <math.h>

// Problem constants: B=64, N=512, d=64
#define NB 64
#define NN 512
#define ND 64

#define LOG2E 1.4426950408889634f
#define LN2   0.6931471805599453f
#define RING  16                      // prefetch ring depth (columns in flight)
#define NINF  __int_as_float(0xFF800000u)   // -inf

typedef __attribute__((ext_vector_type(8))) short  bf16x8;  // 8 bf16 in 4 VGPRs
typedef __attribute__((ext_vector_type(4))) float  f32x4;

// fp32 -> bf16 bits, round-to-nearest-even (inputs are finite)
static __device__ __forceinline__ unsigned short f2bf(float f) {
    unsigned u = __float_as_uint(f);
    u += 0x7FFFu + ((u >> 16) & 1u);
    return (unsigned short)(u >> 16);
}

// ---------------------------------------------------------------------------
// Kernel 0 (pack): X,Y (f32 row-major) -> bf16 in MFMA-fragment order, plus
// fp32 row norms (R12/R13-proven, unchanged).
// ---------------------------------------------------------------------------
__global__ __launch_bounds__(256) void pack_kernel(const float* __restrict__ X,
                                                   const float* __restrict__ Y,
                                                   unsigned short* __restrict__ Xp,
                                                   unsigned short* __restrict__ Yp,
                                                   float* __restrict__ nx,
                                                   float* __restrict__ ny) {
    const int gid = blockIdx.x * 256 + threadIdx.x;   // row id, 0..NB*NN-1
    const float* src;
    unsigned short* dst;
    float* ndst;
    if (blockIdx.y == 0) { src = X + (size_t)gid * ND; dst = Xp; ndst = nx; }
    else                 { src = Y + (size_t)gid * ND; dst = Yp; ndst = ny; }

    float v[ND];
    float s = 0.f;
    #pragma unroll
    for (int k = 0; k < ND; k += 4) {
        float4 f = *(const float4*)(src + k);
        v[k] = f.x; v[k + 1] = f.y; v[k + 2] = f.z; v[k + 3] = f.w;
        s += f.x * f.x + f.y * f.y + f.z * f.z + f.w * f.w;
    }
    ndst[gid] = s;

    const int b  = gid >> 9;
    const int i  = gid & 511;
    const int it = i >> 4;             // 16-row tile
    const int lm = i & 15;             // row within tile
    #pragma unroll
    for (int h = 0; h < 2; ++h) {
        #pragma unroll
        for (int q = 0; q < 4; ++q) {
            unsigned w[4];
            #pragma unroll
            for (int m = 0; m < 4; ++m) {
                const int c = h * 32 + q * 8 + 2 * m;
                w[m] = (unsigned)f2bf(v[c]) | ((unsigned)f2bf(v[c + 1]) << 16);
            }
            uint4 pkt; pkt.x = w[0]; pkt.y = w[1]; pkt.z = w[2]; pkt.w = w[3];
            *(uint4*)(dst + ((((size_t)b * 32 + it) * 2 + h) << 9)
                          + (size_t)(q * 16 + lm) * 8) = pkt;
        }
    }
}

// ---------------------------------------------------------------------------
// Kernel 1 (MFMA): Wt[b][i][j] = bf16( exp2(16 - log2e*||X[b][i]-Y[b][j]||) )
// (R13-proven, unchanged: packed coalesced fragment loads, dwordx2 stores.)
// ---------------------------------------------------------------------------
__global__ __launch_bounds__(256) void cdist_kernel(const unsigned short* __restrict__ Xp,
                                                    const unsigned short* __restrict__ Yp,
                                                    const float* __restrict__ nx,
                                                    const float* __restrict__ ny,
                                                    unsigned short* __restrict__ Wt) {
    const int b  = blockIdx.z;
    const int ib = blockIdx.x * 128;   // i base (X rows)
    const int jb = blockIdx.y * 128;   // j base (Y rows)
    const int t  = threadIdx.x;

    const int wave = t >> 6;
    const int wi   = (wave & 1) * 64;   // i offset of this wave's 64x64 tile
    const int wj   = (wave >> 1) * 64;  // j offset
    const int lane = t & 63;
    const int lm   = lane & 15;
    const int quad = lane >> 4;

    f32x4 acc[4][4];
    #pragma unroll
    for (int mt = 0; mt < 4; ++mt)
        #pragma unroll
        for (int nt = 0; nt < 4; ++nt)
            acc[mt][nt] = (f32x4){0.f, 0.f, 0.f, 0.f};

    const int jt0 = (jb + wj) >> 4;    // Y tile base
    const int it0 = (ib + wi) >> 4;    // X tile base

    #pragma unroll
    for (int h = 0; h < 2; ++h) {
        bf16x8 Af[4], Bf[4];
        #pragma unroll
        for (int mt = 0; mt < 4; ++mt)   // A from Y tiles (m = j dim)
            Af[mt] = *(const bf16x8*)(Yp
                + ((((size_t)b * 32 + jt0 + mt) * 2 + h) << 9) + (size_t)lane * 8);
        #pragma unroll
        for (int nt = 0; nt < 4; ++nt)   // B from X tiles (n = i dim)
            Bf[nt] = *(const bf16x8*)(Xp
                + ((((size_t)b * 32 + it0 + nt) * 2 + h) << 9) + (size_t)lane * 8);
        #pragma unroll
        for (int mt = 0; mt < 4; ++mt)
            #pragma unroll
            for (int nt = 0; nt < 4; ++nt)
                acc[mt][nt] = __builtin_amdgcn_mfma_f32_16x16x32_bf16(
                    Af[mt], Bf[nt], acc[mt][nt], 0, 0, 0);
    }

    float nxv[4];
    float4 nyv[4];
    #pragma unroll
    for (int nt = 0; nt < 4; ++nt)
        nxv[nt] = nx[(size_t)b * NN + ib + wi + nt * 16 + lm];
    #pragma unroll
    for (int mt = 0; mt < 4; ++mt)
        nyv[mt] = *(const float4*)(ny + (size_t)b * NN + jb + wj + mt * 16 + quad * 4);

    #pragma unroll
    for (int nt = 0; nt < 4; ++nt) {
        const int i = ib + wi + nt * 16 + lm;
        unsigned short* Drow = Wt + ((size_t)b * NN + i) * NN + jb + wj;
        #pragma unroll
        for (int mt = 0; mt < 4; ++mt) {
            const float* nyp = (const float*)&nyv[mt];
            unsigned a[4];
            #pragma unroll
            for (int r = 0; r < 4; ++r) {
                float d2 = nyp[r] + nxv[nt] - 2.0f * acc[mt][nt][r];
                float w  = __builtin_amdgcn_exp2f(16.0f - LOG2E * sqrtf(fmaxf(d2, 0.f)));
                a[r] = __float_as_uint(w) + 0x8000u;   // round-half-up to bf16
            }
            uint2 pkt;
            pkt.x = (a[0] >> 16) | (a[1] & 0xFFFF0000u);
            pkt.y = (a[2] >> 16) | (a[3] & 0xFFFF0000u);
            *(uint2*)(Drow + mt * 16 + quad * 4) = pkt;
        }
    }
}

// ---------------------------------------------------------------------------
// Kernel 2: soft-DTW DP, exp-domain chain (R11-R13-proven math), now split
// across TWO PIPELINED WAVES per batch. Wave w owns rows w*256+1..w*256+256,
// 4 rows/lane (half the per-step chain). Row-256 handoff: wave 0's lanes
// write absolute h = log2(F) into LDS h0[col] (renorm-invariant, R9-proven
// mechanism); wave 1 preloads 64 values/chunk into a register and rotates it
// to lane 0 with one DPP wave_shl per step. Wave 1 lags 2 chunks (128 steps)
// behind wave 0; 11 barrier-separated 64-step wall chunks guarantee the
// producer-consumer margin (col c complete at wave0-step c+62 < consumer
// preload time (w*64) for all consumed cols — verified: max col = w*64-64).
// ---------------------------------------------------------------------------
static __device__ __forceinline__ float dpp_shr1(float x, float old) {
    return __int_as_float(__builtin_amdgcn_update_dpp(
        __float_as_int(old), __float_as_int(x), 0x138, 0xf, 0xf, false));
}
static __device__ __forceinline__ float dpp_shl1(float x) {
    return __int_as_float(__builtin_amdgcn_update_dpp(
        0, __float_as_int(x), 0x130, 0xf, 0xf, false));
}

static __device__ __forceinline__ void dtw_step4(
    bool W1, bool DOACT, bool DOGUARD, bool DOCLAMP, bool DOREN,
    int ss, int u, int t, const unsigned short* __restrict__ Wb, int ib,
    uint2* ring, float* L, float& diagHold, float& h, float& Otf,
    float& hbuf, float* __restrict__ h0)
{
    // intra-wave handoff: lane t gets lane t-1's h (lane 0: -inf)
    float recvH = dpp_shr1(h, NINF);
    if (W1) {
        recvH = (t == 0) ? hbuf : recvH;   // lane 0: cross-wave value from LDS
        hbuf  = dpp_shl1(hbuf);            // rotate: next step's value to lane 0
    }
    if (DOACT) { if (ss == t && (t > 0 || W1)) Otf = -recvH; }  // adopt scale

    const float up0   = __builtin_amdgcn_exp2f(fminf(recvH + Otf, 80.0f));
    const float diag0 = diagHold;          // 2^16 * F[row ib][j-1], stored dom.
    diagHold = up0 * 65536.0f;             // 2^16 * F[row ib][j] for next step

    const int j = ss - t + 1;
    const uint2 c = ring[u];

    // refill slot u for step ss+RING (unconditional; overrun reads dead data)
    {
        int jn = j + RING;
        if (DOCLAMP) jn = jn < 1 ? 1 : jn;
        ring[u] = *(const uint2*)(Wb + (size_t)(jn - 1) * NN + ib);
    }

    bool act = true;
    if (DOGUARD) act = (j >= 1) && (j <= NN);
    if (act) {
        float dd[4];                       // bf16 -> f32: shl/and, exact
        dd[0] = __uint_as_float(c.x << 16);
        dd[1] = __uint_as_float(c.x & 0xFFFF0000u);
        dd[2] = __uint_as_float(c.y << 16);
        dd[3] = __uint_as_float(c.y & 0xFFFF0000u);

        float pre[4], cc[4];
        pre[0] = diag0 + L[0];
        #pragma unroll
        for (int k = 1; k < 4; ++k)
            pre[k] = fmaf(65536.0f, L[k - 1], L[k]);
        #pragma unroll
        for (int k = 0; k < 4; ++k) cc[k] = dd[k] * pre[k];
        float r = up0;
        #pragma unroll
        for (int k = 0; k < 4; ++k) {      // serial chain: 4 fma
            r = fmaf(dd[k], r, cc[k]);
            L[k] = r;
        }

        if (DOREN) {   // branchless full normalization: max(L) -> [1,2)
            float m4 = fmaxf(fmaxf(L[0], L[1]), fmaxf(L[2], L[3]));
            const int   e  = (int)(__float_as_uint(m4) >> 23) - 127;
            const float sc = __uint_as_float((unsigned)(127 - e) << 23); // 2^-e
            #pragma unroll
            for (int k = 0; k < 4; ++k) L[k] *= sc;
            diagHold *= sc;
            Otf -= (float)e;
        }

        h = __builtin_amdgcn_logf(L[3]) - Otf;   // absolute log2-domain handoff
        if (!W1) h0[j] = h;                // publish row-boundary value
    }
}

static __device__ __forceinline__ void run_chunk(
    bool W1, bool ACT, bool GUARD, bool CLAMP, int base,
    int t, const unsigned short* __restrict__ Wb, int ib,
    uint2* ring, float* L, float& diagHold, float& h, float& Otf,
    float& hbuf, float* __restrict__ h0)
{
    for (int sb = 0; sb < 64; sb += RING)
        #pragma unroll
        for (int u = 0; u < RING; ++u)
            dtw_step4(W1, ACT, GUARD, CLAMP, (u & 1) == 1,
                      base + sb + u, u, t, Wb, ib, ring, L,
                      diagHold, h, Otf, hbuf, h0);
}

__global__ __launch_bounds__(128) void dtw_kernel(const unsigned short* __restrict__ Wt,
                                                  float* __restrict__ out) {
    __shared__ float h0[584];
    const int b    = blockIdx.x;
    const int tid  = threadIdx.x;
    const int t    = tid & 63;
    const int wave = tid >> 6;
    const unsigned short* __restrict__ Wb = Wt + (size_t)b * NN * NN;
    const int ib = wave * 256 + 4 * t;     // first owned row - 1

    float L[4] = {0.f, 0.f, 0.f, 0.f};     // F(boundary) = 0
    float diagHold = (wave == 0 && t == 0) ? 65536.0f : 0.0f; // 2^16*F[0][0]
    float h = NINF, Otf = 0.0f, hbuf = NINF;

    uint2 ring[RING];
    #pragma unroll
    for (int u = 0; u < RING; ++u) {
        int col = u - t + 1;
        col = col < 1 ? 1 : col;           // clamp; dead if OOB
        ring[u] = *(const uint2*)(Wb + (size_t)(col - 1) * NN + ib);
    }

    for (int wall = 0; wall < 11; ++wall) {
        const int ch = wave ? wall - 2 : wall;   // wave 1 lags 2 chunks
        if (wave == 0) {
            if (ch == 0)
                run_chunk(false, true,  true,  true,  0,      t, Wb, ib, ring, L, diagHold, h, Otf, hbuf, h0);
            else if (ch >= 1 && ch <= 7)
                run_chunk(false, false, false, false, ch*64,  t, Wb, ib, ring, L, diagHold, h, Otf, hbuf, h0);
            else if (ch == 8)
                run_chunk(false, false, true,  false, 512,    t, Wb, ib, ring, L, diagHold, h, Otf, hbuf, h0);
        } else {
            if (ch == 0)
                run_chunk(true,  true,  true,  true,  0,      t, Wb, ib, ring, L, diagHold, h, Otf, hbuf, h0);
            else if (ch >= 1 && ch <= 7)
                run_chunk(true,  false, false, false, ch*64,  t, Wb, ib, ring, L, diagHold, h, Otf, hbuf, h0);
            else if (ch == 8)
                run_chunk(true,  false, true,  false, 512,    t, Wb, ib, ring, L, diagHold, h, Otf, hbuf, h0);
        }
        __syncthreads();
        // preload wave 1's next-chunk boundary values (cols base+1..base+64)
        if (wave && wall >= 1 && wall <= 9)
            hbuf = h0[(wall - 1) * 64 + 1 + t];
    }

    // F[512][512] = 2^(16*1024) e^{-R}; h = log2 F (absolute)
    if (wave == 1 && t == 63) out[b] = (16384.0f - h) * LN2;
}

extern "C" void kernel_launch(void* const* d_in, const int* in_sizes, int n_in,
                              void* d_out, int out_size, void* d_ws, size_t ws_size,
                              hipStream_t stream) {
    const float* X = (const float*)d_in[0];
    const float* Y = (const float*)d_in[1];
    float* out = (float*)d_out;

    // workspace layout (ws >= 64 MB):
    //   [0, 32 MB)      Wt  : bf16 W matrix, layout [b][i][j]
    //   [32, 36 MB)     Xp  : packed bf16 X fragments
    //   [36, 40 MB)     Yp  : packed bf16 Y fragments
    //   [40 MB, +128KB) nx  : fp32 row norms of X
    //   [+128KB,+256KB) ny  : fp32 row norms of Y
    char* ws = (char*)d_ws;
    unsigned short* Wt = (unsigned short*)(ws);
    unsigned short* Xp = (unsigned short*)(ws + (33554432));
    unsigned short* Yp = (unsigned short*)(ws + (33554432 + 4194304));
    float* nx = (float*)(ws + (33554432 + 2 * 4194304));
    float* ny = (float*)(ws + (33554432 + 2 * 4194304 + 131072));

    pack_kernel<<<dim3(NB * NN / 256, 2), 256, 0, stream>>>(X, Y, Xp, Yp, nx, ny);
    cdist_kernel<<<dim3(4, 4, NB), 256, 0, stream>>>(Xp, Yp, nx, ny, Wt);
    dtw_kernel<<<NB, 128, 0, stream>>>(Wt, out);
}